// Round 17
// baseline (1926.498 us; speedup 1.0000x reference)
//
#include <hip/hip_runtime.h>
#include <stdint.h>

typedef unsigned int u32;
typedef unsigned short u16;
typedef __attribute__((ext_vector_type(8))) short bf16x8;   // 8 bf16 = 4 VGPRs
typedef __attribute__((ext_vector_type(4))) float f32x4;

#define DEV __device__ __forceinline__
#define BN_EPS 1e-5f

DEV float bf2f(u16 u){ return __uint_as_float(((u32)u) << 16); }
DEV u16 f2bf(float f){ u32 x = __float_as_uint(f); return (u16)((x + 0x7FFFu + ((x >> 16) & 1u)) >> 16); }

// ---------------------------------------------------------------- DPP wave64 argmax/argmin reduce
template<int CTRL, int RMASK, bool MAXOP>
DEV void dpp_step(float& d, u32& i){
  int ds = __float_as_int(d);
  int is = (int)i;
  int dn_ = __builtin_amdgcn_update_dpp(ds, ds, CTRL, RMASK, 0xf, false);
  int in_ = __builtin_amdgcn_update_dpp(is, is, CTRL, RMASK, 0xf, false);
  float dn = __int_as_float(dn_);
  u32 ii = (u32)in_;
  bool take = MAXOP ? (dn > d || (dn == d && ii < i))
                    : (dn < d || (dn == d && ii < i));
  if (take){ d = dn; i = ii; }
}

// full butterfly-equivalent reduce; winner (value,index) valid in lane 63
template<bool MAXOP>
DEV void dpp_arg_reduce_vi(float& d, u32& i, float& outd, u32& outi){
  dpp_step<0x111, 0xf, MAXOP>(d, i);
  dpp_step<0x112, 0xf, MAXOP>(d, i);
  dpp_step<0x114, 0xf, MAXOP>(d, i);
  dpp_step<0x118, 0xf, MAXOP>(d, i);
  dpp_step<0x142, 0xa, MAXOP>(d, i);
  dpp_step<0x143, 0xc, MAXOP>(d, i);
  outi = (u32)__builtin_amdgcn_readlane((int)i, 63);
  outd = __int_as_float(__builtin_amdgcn_readlane(__float_as_int(d), 63));
}

template<bool MAXOP>
DEV u32 dpp_arg_reduce(float& d, u32& i){
  float od; u32 oi;
  dpp_arg_reduce_vi<MAXOP>(d, i, od, oi);
  return oi;
}

// ---------------------------------------------------------------- ws-too-small fallback
__global__ void kfb(float* out, int n, float code){
  int i = blockIdx.x * 256 + threadIdx.x;
  if (i < n) out[i] = (i == 0) ? code : 0.f;
}

// cast weights to bf16
__global__ void kcast_bf(const float* __restrict__ src, int rows, int cols, int srcStride, int colOff,
                         u16* __restrict__ dst){
  int i = blockIdx.x * 256 + threadIdx.x;
  if (i >= rows * cols) return;
  int r = i / cols, c = i - r * cols;
  dst[r * cols + c] = f2bf(src[r * srcStride + colOff + c]);
}

// ---------------------------------------------------------------- stage A: BN1 stats (deterministic)
__global__ __launch_bounds__(256) void kA_stats(const float* __restrict__ x, const float* __restrict__ w,
                                                const float* __restrict__ g, const float* __restrict__ b,
                                                float* __restrict__ sc, float* __restrict__ sh){
  int c = blockIdx.x, t = threadIdx.x;
  float wr[6];
#pragma unroll
  for (int j = 0; j < 6; ++j) wr[j] = w[c * 6 + j];
  float s = 0.f, ss = 0.f;
  for (int i = t; i < 32768; i += 256){
    int bb = i >> 10, n = i & 1023;
    const float* xb = x + bb * 6144 + n;
    float y = 0.f;
#pragma unroll
    for (int j = 0; j < 6; ++j) y += wr[j] * xb[j * 1024];
    s += y; ss += y * y;
  }
  __shared__ float rs[256], rq[256];
  rs[t] = s; rq[t] = ss; __syncthreads();
  for (int k = 128; k >= 1; k >>= 1){
    if (t < k){ rs[t] += rs[t + k]; rq[t] += rq[t + k]; }
    __syncthreads();
  }
  if (t == 0){
    float m = rs[0] * (1.f / 32768.f), e2 = rq[0] * (1.f / 32768.f);
    float var = e2 - m * m; if (var < 0.f) var = 0.f;
    float scv = g[c] * rsqrtf(var + BN_EPS);
    sc[c] = scv; sh[c] = b[c] - m * scv;
  }
}

// stage A apply -> featT bf16 [b][n][64]
__global__ __launch_bounds__(256) void kA_feat(const float* __restrict__ x, const float* __restrict__ w,
                                               const float* __restrict__ sc, const float* __restrict__ sh,
                                               u16* __restrict__ featT){
  int b = blockIdx.x >> 2, t = threadIdx.x;
  int n = ((blockIdx.x & 3) << 8) + t;
  __shared__ float wl[384], scl[64], shl[64];
  for (int u = t; u < 384; u += 256) wl[u] = w[u];
  if (t < 64){ scl[t] = sc[t]; shl[t] = sh[t]; }
  __syncthreads();
  float v[6];
  const float* xb = x + b * 6144 + n;
#pragma unroll
  for (int j = 0; j < 6; ++j) v[j] = xb[j * 1024];
  u32* row = (u32*)(featT + ((size_t)b * 1024 + n) * 64);
#pragma unroll
  for (int c2 = 0; c2 < 32; ++c2){
    float y0 = 0.f, y1 = 0.f;
#pragma unroll
    for (int j = 0; j < 6; ++j){
      y0 += wl[(2 * c2) * 6 + j] * v[j];
      y1 += wl[(2 * c2 + 1) * 6 + j] * v[j];
    }
    y0 = fmaxf(scl[2 * c2] * y0 + shl[2 * c2], 0.f);
    y1 = fmaxf(scl[2 * c2 + 1] * y1 + shl[2 * c2 + 1], 0.f);
    row[c2] = (u32)f2bf(y0) | ((u32)f2bf(y1) << 16);
  }
}

// ---------------------------------------------------------------- x_skip pre-act bf16 [b][1024][256]
__global__ __launch_bounds__(256) void kxskip_pre(const u16* __restrict__ featT, const float* __restrict__ w2,
                                                  u16* __restrict__ xpre){
  int b = blockIdx.x >> 4, ot = blockIdx.x & 15, m = threadIdx.x;
  __shared__ float w2s[64][65];
  for (int u = threadIdx.x; u < 64 * 64; u += 256){
    int o = u >> 6, c = u & 63;
    w2s[o][c] = w2[(size_t)(ot * 64 + o) * 64 + c];
  }
  __syncthreads();
  float feat[64];
  const uint4* fr = (const uint4*)(featT + ((size_t)b * 1024 + 4 * m) * 64);
#pragma unroll
  for (int q = 0; q < 8; ++q){
    uint4 pv = fr[q];
    u32 wv[4] = {pv.x, pv.y, pv.z, pv.w};
#pragma unroll
    for (int h = 0; h < 4; ++h){
      feat[q * 8 + 2 * h]     = bf2f((u16)(wv[h] & 0xffff));
      feat[q * 8 + 2 * h + 1] = bf2f((u16)(wv[h] >> 16));
    }
  }
  u16* xb = xpre + ((size_t)b * 1024 + ot * 64) * 256 + m;
  for (int o = 0; o < 64; ++o){
    float acc = 0.f;
#pragma unroll
    for (int c = 0; c < 64; ++c) acc += w2s[o][c] * feat[c];
    xb[(size_t)o * 256] = f2bf(acc);
  }
}

__global__ __launch_bounds__(256) void kxskip_stats(const u16* __restrict__ xpre, const float* __restrict__ g,
                                                    const float* __restrict__ b, float* __restrict__ sc,
                                                    float* __restrict__ sh){
  int o = blockIdx.x, t = threadIdx.x;
  float s = 0.f, ss = 0.f;
  for (int i = t; i < 8192; i += 256){
    int bb = i >> 8, m = i & 255;
    float v = bf2f(xpre[((size_t)bb * 1024 + o) * 256 + m]);
    s += v; ss += v * v;
  }
  __shared__ float rs[256], rq[256];
  rs[t] = s; rq[t] = ss; __syncthreads();
  for (int k = 128; k >= 1; k >>= 1){
    if (t < k){ rs[t] += rs[t + k]; rq[t] += rq[t + k]; }
    __syncthreads();
  }
  if (t == 0){
    float m = rs[0] * (1.f / 8192.f), e2 = rq[0] * (1.f / 8192.f);
    float var = e2 - m * m; if (var < 0.f) var = 0.f;
    float scv = g[o] * rsqrtf(var + BN_EPS);
    sc[o] = scv; sh[o] = b[o] - m * scv;
  }
}

// ---------------------------------------------------------------- FPS: 4 waves/batch, packed float4 LDS,
// per-wave DPP argmax + cross-wave LDS table combine (double-buffered -> ONE barrier/iter).
// Lattice (max value, min index) is partition-invariant -> selections bit-identical to 1-wave version.
template<int NPTS, int NSAMP, int PSTRIDE>
__global__ __launch_bounds__(256) void kfps4(const float* __restrict__ px_, const float* __restrict__ py_,
                                             const float* __restrict__ pz_, int bstride,
                                             int* __restrict__ fidx, float* __restrict__ nxyz){
  constexpr int PPL = NPTS / 256;
  __shared__ float4 pts[NPTS];
  __shared__ float rbd[2][4];
  __shared__ u32   rbi[2][4];
  int b = blockIdx.x, t = threadIdx.x;
  int wv = t >> 6;
  float dd[PPL];
#pragma unroll
  for (int j = 0; j < PPL; ++j){
    int p = j * 256 + t;
    pts[p] = make_float4(px_[(size_t)b * bstride + p * PSTRIDE],
                         py_[(size_t)b * bstride + p * PSTRIDE],
                         pz_[(size_t)b * bstride + p * PSTRIDE], 0.f);
    dd[j] = 1e10f;
  }
  __syncthreads();
  float4 c0 = pts[0];
  float cx = c0.x, cy = c0.y, cz = c0.z;
  if (t == 0){
    fidx[(size_t)b * NSAMP] = 0;
    nxyz[(size_t)b * NSAMP * 3 + 0] = cx;
    nxyz[(size_t)b * NSAMP * 3 + 1] = cy;
    nxyz[(size_t)b * NSAMP * 3 + 2] = cz;
  }
  int buf = 0;
  for (int s = 1; s < NSAMP; ++s){
    float bd = -1.f; u32 bi = 0;
#pragma unroll
    for (int j = 0; j < PPL; ++j){
      int p = j * 256 + t;
      float4 pt = pts[p];          // per-lane b128 read, stride-1 -> conflict-free
      float dx = __fsub_rn(pt.x, cx);
      float dy = __fsub_rn(pt.y, cy);
      float dz = __fsub_rn(pt.z, cz);
      float d = __fadd_rn(__fadd_rn(__fmul_rn(dx, dx), __fmul_rn(dy, dy)), __fmul_rn(dz, dz));
      float v = fminf(dd[j], d);
      dd[j] = v;
      if (v > bd){ bd = v; bi = (u32)p; }   // strict > keeps lowest p (for fixed t, p grows with j)
    }
    float wbd; u32 wbi;
    dpp_arg_reduce_vi<true>(bd, bi, wbd, wbi);
    if ((t & 63) == 0){ rbd[buf][wv] = wbd; rbi[buf][wv] = wbi; }
    __syncthreads();
    float Bd = rbd[buf][0]; u32 Bi = rbi[buf][0];
#pragma unroll
    for (int w = 1; w < 4; ++w){
      float od = rbd[buf][w]; u32 oi = rbi[buf][w];
      if (od > Bd || (od == Bd && oi < Bi)){ Bd = od; Bi = oi; }
    }
    float4 cw = pts[Bi];          // uniform -> broadcast
    cx = cw.x; cy = cw.y; cz = cw.z;
    if (t == 0){
      fidx[(size_t)b * NSAMP + s] = (int)Bi;
      nxyz[((size_t)b * NSAMP + s) * 3 + 0] = cx;
      nxyz[((size_t)b * NSAMP + s) * 3 + 1] = cy;
      nxyz[((size_t)b * NSAMP + s) * 3 + 2] = cz;
    }
    buf ^= 1;   // double-buffer: next iter's writes can't race this iter's reads (1 barrier apart)
  }
}

// ---------------------------------------------------------------- kNN: DPP argmin, 4 waves/block
template<int NPTS, int SOUT>
__global__ __launch_bounds__(256) void kknn(const float* __restrict__ px_, const float* __restrict__ py_,
                                            const float* __restrict__ pz_, int bstride, int pstride,
                                            const float* __restrict__ cxyz, int* __restrict__ knn){
  constexpr int PPL = NPTS / 64;
  int wid = blockIdx.x * 4 + (threadIdx.x >> 6);
  int lane = threadIdx.x & 63;
  int b = wid / SOUT, s = wid - b * SOUT;
  const float* cb = cxyz + ((size_t)b * SOUT + s) * 3;
  float cx = cb[0], cy = cb[1], cz = cb[2];
  float csq = __fadd_rn(__fadd_rn(__fmul_rn(cx, cx), __fmul_rn(cy, cy)), __fmul_rn(cz, cz));
  float kd[PPL];
#pragma unroll
  for (int j = 0; j < PPL; ++j){
    int p = j * 64 + lane;
    float xx = px_[(size_t)b * bstride + p * pstride];
    float yy = py_[(size_t)b * bstride + p * pstride];
    float zz = pz_[(size_t)b * bstride + p * pstride];
    float psq = __fadd_rn(__fadd_rn(__fmul_rn(xx, xx), __fmul_rn(yy, yy)), __fmul_rn(zz, zz));
    float dot = __fadd_rn(__fadd_rn(__fmul_rn(cx, xx), __fmul_rn(cy, yy)), __fmul_rn(cz, zz));
    kd[j] = __fsub_rn(__fadd_rn(csq, psq), __fmul_rn(2.f, dot));
  }
  int* outp = knn + ((size_t)b * SOUT + s) * 32;
  for (int k = 0; k < 32; ++k){
    float bd = kd[0]; u32 bi = (u32)lane;
#pragma unroll
    for (int j = 1; j < PPL; ++j){
      u32 p = (u32)(j * 64 + lane);
      if (kd[j] < bd){ bd = kd[j]; bi = p; }
    }
    u32 win = dpp_arg_reduce<false>(bd, bi);
    if (lane == 0) outp[k] = (int)win;
#pragma unroll
    for (int j = 0; j < PPL; ++j) if ((u32)(j * 64 + lane) == win) kd[j] = 3e38f;
  }
}

// ---------------------------------------------------------------- pass 0: gather + GEMM1 (MFMA) -> pre1 bf16 + BN1 partials
template<int CIN, int C, int NPTSRC, int SLOG>
__global__ __launch_bounds__(256) void kgm_pre(const u16* __restrict__ featSrc, const int* __restrict__ knnIdx,
                                               const int* __restrict__ fidx, const float* __restrict__ w1f,
                                               const u16* __restrict__ w1bf,
                                               u16* __restrict__ pre1, float* __restrict__ part){
  constexpr int MT  = C / 64;
  constexpr int KS1 = CIN / 32;
  constexpr int P1  = CIN + 8;
  int g = blockIdx.x, t = threadIdx.x, b = g >> SLOG;
  int l = t & 63, wv = t >> 6;
  int lg = l >> 4, ln = l & 15;

  __shared__ int   idxs[32];
  __shared__ float cen[CIN];
  __shared__ float bias[C];
  __shared__ u16   gsT[32][P1];

  if (t < 32) idxs[t] = knnIdx[(size_t)g * 32 + t];
  for (int u = t; u < CIN; u += 256) cen[u] = bf2f(featSrc[((size_t)(b * NPTSRC + fidx[g])) * CIN + u]);
  __syncthreads();

  for (int u = t; u < 32 * CIN / 8; u += 256){
    int k = u & 31, c8 = u >> 5;
    uint4 pv = *(const uint4*)(featSrc + ((size_t)(b * NPTSRC + idxs[k])) * CIN + c8 * 8);
    u32 wvv[4] = {pv.x, pv.y, pv.z, pv.w};
    u32 outw[4];
#pragma unroll
    for (int h = 0; h < 4; ++h){
      float a0 = bf2f((u16)(wvv[h] & 0xffff)) - cen[c8 * 8 + 2 * h];
      float a1 = bf2f((u16)(wvv[h] >> 16))    - cen[c8 * 8 + 2 * h + 1];
      outw[h] = (u32)f2bf(a0) | ((u32)f2bf(a1) << 16);
    }
    *(uint4*)&gsT[k][c8 * 8] = make_uint4(outw[0], outw[1], outw[2], outw[3]);
  }
  if (t < C){
    const float* wr = w1f + (size_t)t * (2 * CIN) + CIN;
    float bs = 0.f;
#pragma unroll 4
    for (int c = 0; c < CIN; ++c) bs += wr[c] * cen[c];
    bias[t] = bs;
  }
  __syncthreads();

  f32x4 acc[MT][2];
#pragma unroll
  for (int mt = 0; mt < MT; ++mt){ acc[mt][0] = (f32x4)0.f; acc[mt][1] = (f32x4)0.f; }
#pragma unroll
  for (int ks = 0; ks < KS1; ++ks){
    int c0 = ks * 32 + lg * 8;
    bf16x8 bfr0 = *(const bf16x8*)&gsT[ln][c0];
    bf16x8 bfr1 = *(const bf16x8*)&gsT[16 + ln][c0];
#pragma unroll
    for (int mt = 0; mt < MT; ++mt){
      int o0 = wv * (C / 4) + mt * 16;
      bf16x8 afr = *(const bf16x8*)(w1bf + (size_t)(o0 + ln) * CIN + c0);
      acc[mt][0] = __builtin_amdgcn_mfma_f32_16x16x32_bf16(afr, bfr0, acc[mt][0], 0, 0, 0);
      acc[mt][1] = __builtin_amdgcn_mfma_f32_16x16x32_bf16(afr, bfr1, acc[mt][1], 0, 0, 0);
    }
  }

#pragma unroll
  for (int mt = 0; mt < MT; ++mt){
    int obase = wv * (C / 4) + mt * 16 + lg * 4;
#pragma unroll
    for (int j = 0; j < 4; ++j){
      int o = obase + j;
      float bv = bias[o];
      float vA = acc[mt][0][j] + bv, vB = acc[mt][1][j] + bv;
      u16* pp = pre1 + ((size_t)g * C + o) * 32 + ln;
      pp[0]  = f2bf(vA);
      pp[16] = f2bf(vB);
      float s = vA + vB, ss = vA * vA + vB * vB;
#pragma unroll
      for (int mk = 1; mk < 16; mk <<= 1){ s += __shfl_xor(s, mk, 64); ss += __shfl_xor(ss, mk, 64); }
      if (ln == 0){
        part[((size_t)g * C + o) * 2 + 0] = s;
        part[((size_t)g * C + o) * 2 + 1] = ss;
      }
    }
  }
}

// ---------------------------------------------------------------- pass 2: pre1 -> BN1+ReLU -> GEMM2 (MFMA) -> partials + pool
template<int C>
__global__ __launch_bounds__(256) void kgm_post(const u16* __restrict__ pre1,
                                                const float* __restrict__ sc1g, const float* __restrict__ sh1g,
                                                const u16* __restrict__ w2bf, const float* __restrict__ gp,
                                                float* __restrict__ part, float* __restrict__ pooledPre){
  constexpr int MT  = C / 64;
  constexpr int KS2 = C / 32;
  constexpr int P2  = C + 8;
  int g = blockIdx.x, t = threadIdx.x;
  int l = t & 63, wv = t >> 6;
  int lg = l >> 4, ln = l & 15;

  __shared__ u16   act2[32][P2];
  __shared__ float sc1s[C], sh1s[C];
  for (int u = t; u < C; u += 256){ sc1s[u] = sc1g[u]; sh1s[u] = sh1g[u]; }
  __syncthreads();

  for (int u = t; u < C * 4; u += 256){
    uint4 pv = *(const uint4*)(pre1 + (size_t)g * C * 32 + (size_t)u * 8);
    int o = u >> 2, k0 = (u & 3) << 3;
    float s1 = sc1s[o], h1 = sh1s[o];
    u32 wvv[4] = {pv.x, pv.y, pv.z, pv.w};
#pragma unroll
    for (int h = 0; h < 4; ++h){
      float a0 = fmaxf(s1 * bf2f((u16)(wvv[h] & 0xffff)) + h1, 0.f);
      float a1 = fmaxf(s1 * bf2f((u16)(wvv[h] >> 16))    + h1, 0.f);
      act2[k0 + 2 * h][o]     = f2bf(a0);
      act2[k0 + 2 * h + 1][o] = f2bf(a1);
    }
  }
  __syncthreads();

  f32x4 acc[MT][2];
#pragma unroll
  for (int mt = 0; mt < MT; ++mt){ acc[mt][0] = (f32x4)0.f; acc[mt][1] = (f32x4)0.f; }
#pragma unroll
  for (int ks = 0; ks < KS2; ++ks){
    int c0 = ks * 32 + lg * 8;
    bf16x8 bfr0 = *(const bf16x8*)&act2[ln][c0];
    bf16x8 bfr1 = *(const bf16x8*)&act2[16 + ln][c0];
#pragma unroll
    for (int mt = 0; mt < MT; ++mt){
      int o0 = wv * (C / 4) + mt * 16;
      bf16x8 afr = *(const bf16x8*)(w2bf + (size_t)(o0 + ln) * C + c0);
      acc[mt][0] = __builtin_amdgcn_mfma_f32_16x16x32_bf16(afr, bfr0, acc[mt][0], 0, 0, 0);
      acc[mt][1] = __builtin_amdgcn_mfma_f32_16x16x32_bf16(afr, bfr1, acc[mt][1], 0, 0, 0);
    }
  }

#pragma unroll
  for (int mt = 0; mt < MT; ++mt){
    int obase = wv * (C / 4) + mt * 16 + lg * 4;
#pragma unroll
    for (int j = 0; j < 4; ++j){
      float vA = acc[mt][0][j], vB = acc[mt][1][j];
      float s = vA + vB, ss = vA * vA + vB * vB;
      float mx = fmaxf(vA, vB), mn = fminf(vA, vB);
#pragma unroll
      for (int mk = 1; mk < 16; mk <<= 1){
        s += __shfl_xor(s, mk, 64); ss += __shfl_xor(ss, mk, 64);
        mx = fmaxf(mx, __shfl_xor(mx, mk, 64)); mn = fminf(mn, __shfl_xor(mn, mk, 64));
      }
      if (ln == 0){
        int o = obase + j;
        part[((size_t)g * C + o) * 2 + 0] = s;
        part[((size_t)g * C + o) * 2 + 1] = ss;
        pooledPre[(size_t)g * C + o] = (gp[o] >= 0.f) ? mx : mn;
      }
    }
  }
}

// reduce per-group partials -> BN scale/shift (deterministic)
template<int C, int NG>
__global__ __launch_bounds__(256) void kstats_part(const float* __restrict__ part, const float* __restrict__ g_,
                                                   const float* __restrict__ b_, float* __restrict__ sc,
                                                   float* __restrict__ sh){
  int o = blockIdx.x, t = threadIdx.x;
  float s = 0.f, ss = 0.f;
  for (int i = t; i < NG; i += 256){
    s  += part[((size_t)i * C + o) * 2 + 0];
    ss += part[((size_t)i * C + o) * 2 + 1];
  }
  __shared__ float rs[256], rq[256];
  rs[t] = s; rq[t] = ss; __syncthreads();
  for (int k = 128; k >= 1; k >>= 1){
    if (t < k){ rs[t] += rs[t + k]; rq[t] += rq[t + k]; }
    __syncthreads();
  }
  if (t == 0){
    const float inv_n = 1.f / (float)(NG * 32);
    float m = rs[0] * inv_n, e2 = rq[0] * inv_n;
    float var = e2 - m * m; if (var < 0.f) var = 0.f;
    float scv = g_[o] * rsqrtf(var + BN_EPS);
    sc[o] = scv; sh[o] = b_[o] - m * scv;
  }
}

// finalize pooled (stage1): f0feat bf16 [b*512+s][128]
__global__ void kpool_fin1(const float* __restrict__ pooledPre, const float* __restrict__ sc,
                           const float* __restrict__ sh, u16* __restrict__ f0feat){
  int i = blockIdx.x * 256 + threadIdx.x;
  if (i >= 16384 * 128) return;
  int o = i & 127;
  float v = sc[o] * pooledPre[i] + sh[o];
  f0feat[i] = f2bf(fmaxf(v, 0.f));
}

// finalize pooled (stage2): f1T bf16 [b][c][s]
__global__ void kpool_finT(const float* __restrict__ pooledPre, const float* __restrict__ sc,
                           const float* __restrict__ sh, u16* __restrict__ f1T){
  int i = blockIdx.x * 256 + threadIdx.x;
  if (i >= 8192 * 256) return;
  int gg = i >> 8, o = i & 255;
  int b = gg >> 8, s = gg & 255;
  float v = sc[o] * pooledPre[i] + sh[o];
  f1T[((size_t)(b * 256 + o)) * 256 + s] = f2bf(fmaxf(v, 0.f));
}

// ---------------------------------------------------------------- final GEMM: block = (b, 8-o tile), thread = m
__global__ __launch_bounds__(256) void kfinal8(const u16* __restrict__ f1T, const u16* __restrict__ xpre,
                                               const float* __restrict__ scS, const float* __restrict__ shS,
                                               const float* __restrict__ wf, u16* __restrict__ finpre){
  int b = blockIdx.x >> 6, ot = blockIdx.x & 63, m = threadIdx.x;
  int o0 = ot * 8;
  const float* wb = wf + (size_t)o0 * 1280;
  float acc[8];
#pragma unroll
  for (int j = 0; j < 8; ++j) acc[j] = 0.f;
  const u16* fb = f1T + (size_t)b * 256 * 256 + m;
  for (int k = 0; k < 256; ++k){
    float v = bf2f(fb[(size_t)k * 256]);
#pragma unroll
    for (int j = 0; j < 8; ++j) acc[j] = fmaf(wb[(size_t)j * 1280 + k], v, acc[j]);
  }
  const u16* xb = xpre + (size_t)b * 1024 * 256 + m;
  for (int k = 0; k < 1024; ++k){
    float xv = bf2f(xb[(size_t)k * 256]);
    float v = fmaxf(scS[k] * xv + shS[k], 0.f);
#pragma unroll
    for (int j = 0; j < 8; ++j) acc[j] = fmaf(wb[(size_t)j * 1280 + 256 + k], v, acc[j]);
  }
#pragma unroll
  for (int j = 0; j < 8; ++j)
    finpre[((size_t)b * 512 + o0 + j) * 256 + m] = f2bf(acc[j]);
}

__global__ __launch_bounds__(256) void kstats_fin(const u16* __restrict__ finpre, const float* __restrict__ g,
                                                  const float* __restrict__ b, float* __restrict__ sc,
                                                  float* __restrict__ sh){
  int o = blockIdx.x, t = threadIdx.x;
  float s = 0.f, ss = 0.f;
  for (int i = t; i < 8192; i += 256){
    int bb = i >> 8, m = i & 255;
    float v = bf2f(finpre[((size_t)bb * 512 + o) * 256 + m]);
    s += v; ss += v * v;
  }
  __shared__ float rs[256], rq[256];
  rs[t] = s; rq[t] = ss; __syncthreads();
  for (int k = 128; k >= 1; k >>= 1){
    if (t < k){ rs[t] += rs[t + k]; rq[t] += rq[t + k]; }
    __syncthreads();
  }
  if (t == 0){
    float m = rs[0] * (1.f / 8192.f), e2 = rq[0] * (1.f / 8192.f);
    float var = e2 - m * m; if (var < 0.f) var = 0.f;
    float scv = g[o] * rsqrtf(var + BN_EPS);
    sc[o] = scv; sh[o] = b[o] - m * scv;
  }
}

__global__ void kapply(const u16* __restrict__ finpre, const float* __restrict__ sc,
                       const float* __restrict__ sh, float* __restrict__ out){
  int i = blockIdx.x * 256 + threadIdx.x;
  if (i >= 32 * 512 * 256) return;
  int o = (i >> 8) & 511;
  float v = sc[o] * bf2f(finpre[i]) + sh[o];
  out[i] = v > 0.f ? v : 0.2f * v;
}

// ================================================================ host
extern "C" void kernel_launch(void* const* d_in, const int* in_sizes, int n_in,
                              void* d_out, int out_size, void* d_ws, size_t ws_size,
                              hipStream_t stream){
  const float* x    = (const float*)d_in[0];
  const float* w_c1 = (const float*)d_in[1];
  const float* g1   = (const float*)d_in[2];
  const float* b1   = (const float*)d_in[3];
  const float* w_c2 = (const float*)d_in[4];
  const float* g2   = (const float*)d_in[5];
  const float* b2   = (const float*)d_in[6];
  const float* l0w1 = (const float*)d_in[7];
  const float* l0g1 = (const float*)d_in[8];
  const float* l0b1 = (const float*)d_in[9];
  const float* l0w2 = (const float*)d_in[10];
  const float* l0g2 = (const float*)d_in[11];
  const float* l0b2 = (const float*)d_in[12];
  const float* l1w1 = (const float*)d_in[13];
  const float* l1g1 = (const float*)d_in[14];
  const float* l1b1 = (const float*)d_in[15];
  const float* l1w2 = (const float*)d_in[16];
  const float* l1g2 = (const float*)d_in[17];
  const float* l1b2 = (const float*)d_in[18];
  const float* wf   = (const float*)d_in[19];
  const float* gf   = (const float*)d_in[20];
  const float* bfp  = (const float*)d_in[21];
  float* out = (float*)d_out;

  char* ws = (char*)d_ws;
  size_t cur = 0;
  auto alloc = [&](size_t bytes) -> char* {
    char* p = ws + cur;
    cur += (bytes + 255) & ~(size_t)255;
    return p;
  };
  float* sc1  = (float*)alloc(64 * 4);    float* sh1  = (float*)alloc(64 * 4);
  float* scSK = (float*)alloc(1024 * 4);  float* shSK = (float*)alloc(1024 * 4);
  float* scA1 = (float*)alloc(128 * 4);   float* shA1 = (float*)alloc(128 * 4);
  float* scA2 = (float*)alloc(128 * 4);   float* shA2 = (float*)alloc(128 * 4);
  float* scC1 = (float*)alloc(256 * 4);   float* shC1 = (float*)alloc(256 * 4);
  float* scC2 = (float*)alloc(256 * 4);   float* shC2 = (float*)alloc(256 * 4);
  float* scF  = (float*)alloc(512 * 4);   float* shF  = (float*)alloc(512 * 4);
  u16* w1bf1 = (u16*)alloc((size_t)128 * 64 * 2);
  u16* w2bf1 = (u16*)alloc((size_t)128 * 128 * 2);
  u16* w1bf2 = (u16*)alloc((size_t)256 * 128 * 2);
  u16* w2bf2 = (u16*)alloc((size_t)256 * 256 * 2);
  u16*   featT  = (u16*)  alloc((size_t)32 * 1024 * 64 * 2);
  u16*   xpre   = (u16*)  alloc((size_t)32 * 1024 * 256 * 2);
  int*   fidx1  = (int*)  alloc((size_t)32 * 512 * 4);
  float* nxyz1  = (float*)alloc((size_t)32 * 512 * 3 * 4);
  int*   knn1   = (int*)  alloc((size_t)32 * 512 * 32 * 4);
  int*   fidx2  = (int*)  alloc((size_t)32 * 256 * 4);
  float* nxyz2  = (float*)alloc((size_t)32 * 256 * 3 * 4);
  int*   knn2   = (int*)  alloc((size_t)32 * 256 * 32 * 4);
  u16*   pre1   = (u16*)  alloc((size_t)16384 * 128 * 32 * 2);  // == 8192*256*32, reused by stage 2
  float* part   = (float*)alloc((size_t)16384 * 128 * 2 * 4);   // == 8192*256*2, reused by stage 2
  float* pooledPre = (float*)alloc((size_t)16384 * 128 * 4);    // == 8192*256, reused by stage 2
  u16*   f0feat = (u16*)  alloc((size_t)16384 * 128 * 2);
  u16*   f1T    = (u16*)  alloc((size_t)32 * 256 * 256 * 2);
  u16*   finpre = (u16*)  alloc((size_t)32 * 512 * 256 * 2);

  if (cur > ws_size){
    float code = -1000.f - (float)(ws_size >> 20);
    kfb<<<(out_size + 255) / 256, 256, 0, stream>>>(out, out_size, code);
    return;
  }

  // bf16 weight casts (left half of w1; full w2)
  kcast_bf<<<(128 * 64 + 255) / 256, 256, 0, stream>>>(l0w1, 128, 64, 128, 0, w1bf1);
  kcast_bf<<<(128 * 128 + 255) / 256, 256, 0, stream>>>(l0w2, 128, 128, 128, 0, w2bf1);
  kcast_bf<<<(256 * 128 + 255) / 256, 256, 0, stream>>>(l1w1, 256, 128, 256, 0, w1bf2);
  kcast_bf<<<(256 * 256 + 255) / 256, 256, 0, stream>>>(l1w2, 256, 256, 256, 0, w2bf2);

  // stage A
  kA_stats<<<64, 256, 0, stream>>>(x, w_c1, g1, b1, sc1, sh1);
  kA_feat<<<128, 256, 0, stream>>>(x, w_c1, sc1, sh1, featT);

  // x_skip
  kxskip_pre<<<512, 256, 0, stream>>>(featT, w_c2, xpre);
  kxskip_stats<<<1024, 256, 0, stream>>>(xpre, g2, b2, scSK, shSK);

  // stage 1 selections (4-wave FPS)
  kfps4<1024, 512, 1><<<32, 256, 0, stream>>>(x, x + 1024, x + 2048, 6144, fidx1, nxyz1);
  kknn<1024, 512><<<32 * 512 / 4, 256, 0, stream>>>(x, x + 1024, x + 2048, 6144, 1, nxyz1, knn1);

  // stage 1 local_op (pre -> stats -> post)
  kgm_pre<64, 128, 1024, 9><<<16384, 256, 0, stream>>>(featT, knn1, fidx1, l0w1, w1bf1, pre1, part);
  kstats_part<128, 16384><<<128, 256, 0, stream>>>(part, l0g1, l0b1, scA1, shA1);
  kgm_post<128><<<16384, 256, 0, stream>>>(pre1, scA1, shA1, w2bf1, l0g2, part, pooledPre);
  kstats_part<128, 16384><<<128, 256, 0, stream>>>(part, l0g2, l0b2, scA2, shA2);
  kpool_fin1<<<8192, 256, 0, stream>>>(pooledPre, scA2, shA2, f0feat);

  // stage 2 selections
  kfps4<512, 256, 3><<<32, 256, 0, stream>>>(nxyz1, nxyz1 + 1, nxyz1 + 2, 1536, fidx2, nxyz2);
  kknn<512, 256><<<32 * 256 / 4, 256, 0, stream>>>(nxyz1, nxyz1 + 1, nxyz1 + 2, 1536, 3, nxyz2, knn2);

  // stage 2 local_op
  kgm_pre<128, 256, 512, 8><<<8192, 256, 0, stream>>>(f0feat, knn2, fidx2, l1w1, w1bf2, pre1, part);
  kstats_part<256, 8192><<<256, 256, 0, stream>>>(part, l1g1, l1b1, scC1, shC1);
  kgm_post<256><<<8192, 256, 0, stream>>>(pre1, scC1, shC1, w2bf2, l1g2, part, pooledPre);
  kstats_part<256, 8192><<<256, 256, 0, stream>>>(part, l1g2, l1b2, scC2, shC2);
  kpool_finT<<<8192, 256, 0, stream>>>(pooledPre, scC2, shC2, f1T);

  // final
  kfinal8<<<2048, 256, 0, stream>>>(f1T, xpre, scSK, shSK, wf, finpre);
  kstats_fin<<<512, 256, 0, stream>>>(finpre, gf, bfp, scF, shF);
  kapply<<<16384, 256, 0, stream>>>(finpre, scF, shF, out);
}

// Round 18
// 1560.002 us; speedup vs baseline: 1.2349x; 1.2349x over previous
//
#include <hip/hip_runtime.h>
#include <stdint.h>

typedef unsigned int u32;
typedef unsigned short u16;
typedef __attribute__((ext_vector_type(8))) short bf16x8;   // 8 bf16 = 4 VGPRs
typedef __attribute__((ext_vector_type(4))) float f32x4;

#define DEV __device__ __forceinline__
#define BN_EPS 1e-5f

DEV float bf2f(u16 u){ return __uint_as_float(((u32)u) << 16); }
DEV u16 f2bf(float f){ u32 x = __float_as_uint(f); return (u16)((x + 0x7FFFu + ((x >> 16) & 1u)) >> 16); }

// ---------------------------------------------------------------- DPP helpers
template<int CTRL, int RMASK>
DEV float dppf(float v){
  int r = __builtin_amdgcn_update_dpp(__float_as_int(v), __float_as_int(v), CTRL, RMASK, 0xf, false);
  return __int_as_float(r);
}
template<int CTRL, int RMASK>
DEV u32 dppu(u32 v){
  return (u32)__builtin_amdgcn_update_dpp((int)v, (int)v, CTRL, RMASK, 0xf, false);
}

// two-phase wave64 arg-reduce: (1) value lattice via fmax/fmin DPP ladder -> M in lane63;
// (2) min-index among holders of M via umin DPP ladder. Bit-identical to combined tiebreak reduce.
template<bool MAXOP>
DEV u32 arg_reduce2(float bd, u32 bi){
  float m = bd;
  if (MAXOP){
    m = fmaxf(m, dppf<0x111, 0xf>(m));
    m = fmaxf(m, dppf<0x112, 0xf>(m));
    m = fmaxf(m, dppf<0x114, 0xf>(m));
    m = fmaxf(m, dppf<0x118, 0xf>(m));
    m = fmaxf(m, dppf<0x142, 0xa>(m));
    m = fmaxf(m, dppf<0x143, 0xc>(m));
  } else {
    m = fminf(m, dppf<0x111, 0xf>(m));
    m = fminf(m, dppf<0x112, 0xf>(m));
    m = fminf(m, dppf<0x114, 0xf>(m));
    m = fminf(m, dppf<0x118, 0xf>(m));
    m = fminf(m, dppf<0x142, 0xa>(m));
    m = fminf(m, dppf<0x143, 0xc>(m));
  }
  float M = __int_as_float(__builtin_amdgcn_readlane(__float_as_int(m), 63));
  u32 key = (bd == M) ? bi : 0xFFFFFFFFu;
  key = min(key, dppu<0x111, 0xf>(key));
  key = min(key, dppu<0x112, 0xf>(key));
  key = min(key, dppu<0x114, 0xf>(key));
  key = min(key, dppu<0x118, 0xf>(key));
  key = min(key, dppu<0x142, 0xa>(key));
  key = min(key, dppu<0x143, 0xc>(key));
  return (u32)__builtin_amdgcn_readlane((int)key, 63);
}

// ---------------------------------------------------------------- ws-too-small fallback
__global__ void kfb(float* out, int n, float code){
  int i = blockIdx.x * 256 + threadIdx.x;
  if (i < n) out[i] = (i == 0) ? code : 0.f;
}

// cast weights to bf16
__global__ void kcast_bf(const float* __restrict__ src, int rows, int cols, int srcStride, int colOff,
                         u16* __restrict__ dst){
  int i = blockIdx.x * 256 + threadIdx.x;
  if (i >= rows * cols) return;
  int r = i / cols, c = i - r * cols;
  dst[r * cols + c] = f2bf(src[r * srcStride + colOff + c]);
}

// ---------------------------------------------------------------- stage A: BN1 stats (deterministic)
__global__ __launch_bounds__(256) void kA_stats(const float* __restrict__ x, const float* __restrict__ w,
                                                const float* __restrict__ g, const float* __restrict__ b,
                                                float* __restrict__ sc, float* __restrict__ sh){
  int c = blockIdx.x, t = threadIdx.x;
  float wr[6];
#pragma unroll
  for (int j = 0; j < 6; ++j) wr[j] = w[c * 6 + j];
  float s = 0.f, ss = 0.f;
  for (int i = t; i < 32768; i += 256){
    int bb = i >> 10, n = i & 1023;
    const float* xb = x + bb * 6144 + n;
    float y = 0.f;
#pragma unroll
    for (int j = 0; j < 6; ++j) y += wr[j] * xb[j * 1024];
    s += y; ss += y * y;
  }
  __shared__ float rs[256], rq[256];
  rs[t] = s; rq[t] = ss; __syncthreads();
  for (int k = 128; k >= 1; k >>= 1){
    if (t < k){ rs[t] += rs[t + k]; rq[t] += rq[t + k]; }
    __syncthreads();
  }
  if (t == 0){
    float m = rs[0] * (1.f / 32768.f), e2 = rq[0] * (1.f / 32768.f);
    float var = e2 - m * m; if (var < 0.f) var = 0.f;
    float scv = g[c] * rsqrtf(var + BN_EPS);
    sc[c] = scv; sh[c] = b[c] - m * scv;
  }
}

// stage A apply -> featT bf16 [b][n][64]
__global__ __launch_bounds__(256) void kA_feat(const float* __restrict__ x, const float* __restrict__ w,
                                               const float* __restrict__ sc, const float* __restrict__ sh,
                                               u16* __restrict__ featT){
  int b = blockIdx.x >> 2, t = threadIdx.x;
  int n = ((blockIdx.x & 3) << 8) + t;
  __shared__ float wl[384], scl[64], shl[64];
  for (int u = t; u < 384; u += 256) wl[u] = w[u];
  if (t < 64){ scl[t] = sc[t]; shl[t] = sh[t]; }
  __syncthreads();
  float v[6];
  const float* xb = x + b * 6144 + n;
#pragma unroll
  for (int j = 0; j < 6; ++j) v[j] = xb[j * 1024];
  u32* row = (u32*)(featT + ((size_t)b * 1024 + n) * 64);
#pragma unroll
  for (int c2 = 0; c2 < 32; ++c2){
    float y0 = 0.f, y1 = 0.f;
#pragma unroll
    for (int j = 0; j < 6; ++j){
      y0 += wl[(2 * c2) * 6 + j] * v[j];
      y1 += wl[(2 * c2 + 1) * 6 + j] * v[j];
    }
    y0 = fmaxf(scl[2 * c2] * y0 + shl[2 * c2], 0.f);
    y1 = fmaxf(scl[2 * c2 + 1] * y1 + shl[2 * c2 + 1], 0.f);
    row[c2] = (u32)f2bf(y0) | ((u32)f2bf(y1) << 16);
  }
}

// ---------------------------------------------------------------- FPS body (256-thread staging, wave0 serial loop)
template<int NPTS, int NSAMP, int PSTRIDE>
DEV void fps_body(const float* __restrict__ px_, const float* __restrict__ py_,
                  const float* __restrict__ pz_, int bstride,
                  int* __restrict__ fidx, float* __restrict__ nxyz, int b){
  constexpr int PPL = NPTS / 64;
  __shared__ float sx[NPTS], sy[NPTS], sz[NPTS];
  int t = threadIdx.x;
  for (int p = t; p < NPTS; p += 256){
    sx[p] = px_[(size_t)b * bstride + p * PSTRIDE];
    sy[p] = py_[(size_t)b * bstride + p * PSTRIDE];
    sz[p] = pz_[(size_t)b * bstride + p * PSTRIDE];
  }
  __syncthreads();
  if (t >= 64) return;          // waves 1-3 retire; wave 0 runs the serial chain
  int lane = t;
  float dd[PPL];
#pragma unroll
  for (int j = 0; j < PPL; ++j) dd[j] = 1e10f;
  float cx = sx[0], cy = sy[0], cz = sz[0];
  if (lane == 0){
    fidx[(size_t)b * NSAMP] = 0;
    nxyz[(size_t)b * NSAMP * 3 + 0] = cx;
    nxyz[(size_t)b * NSAMP * 3 + 1] = cy;
    nxyz[(size_t)b * NSAMP * 3 + 2] = cz;
  }
  for (int s = 1; s < NSAMP; ++s){
    float bd = -1.f; u32 bi = 0;
#pragma unroll
    for (int j = 0; j < PPL; ++j){
      int p = j * 64 + lane;
      float dx = __fsub_rn(sx[p], cx);
      float dy = __fsub_rn(sy[p], cy);
      float dz = __fsub_rn(sz[p], cz);
      float d = __fadd_rn(__fadd_rn(__fmul_rn(dx, dx), __fmul_rn(dy, dy)), __fmul_rn(dz, dz));
      float v = fminf(dd[j], d);
      dd[j] = v;
      if (v > bd){ bd = v; bi = (u32)p; }   // strict > keeps lowest j (np.argmax first-index)
    }
    u32 win = arg_reduce2<true>(bd, bi);
    cx = sx[win]; cy = sy[win]; cz = sz[win];   // uniform LDS broadcast
    if (lane == 0){
      fidx[(size_t)b * NSAMP + s] = (int)win;
      nxyz[((size_t)b * NSAMP + s) * 3 + 0] = cx;
      nxyz[((size_t)b * NSAMP + s) * 3 + 1] = cy;
      nxyz[((size_t)b * NSAMP + s) * 3 + 2] = cz;
    }
  }
}

// ---------------------------------------------------------------- x_skip body (bf16)
DEV void xskip_body(const u16* __restrict__ featT, const float* __restrict__ w2,
                    u16* __restrict__ xpre, int bi){
  int b = bi >> 4, ot = bi & 15, m = threadIdx.x;
  __shared__ float w2s[64][65];
  for (int u = threadIdx.x; u < 64 * 64; u += 256){
    int o = u >> 6, c = u & 63;
    w2s[o][c] = w2[(size_t)(ot * 64 + o) * 64 + c];
  }
  __syncthreads();
  float feat[64];
  const uint4* fr = (const uint4*)(featT + ((size_t)b * 1024 + 4 * m) * 64);
#pragma unroll
  for (int q = 0; q < 8; ++q){
    uint4 pv = fr[q];
    u32 wv[4] = {pv.x, pv.y, pv.z, pv.w};
#pragma unroll
    for (int h = 0; h < 4; ++h){
      feat[q * 8 + 2 * h]     = bf2f((u16)(wv[h] & 0xffff));
      feat[q * 8 + 2 * h + 1] = bf2f((u16)(wv[h] >> 16));
    }
  }
  u16* xb = xpre + ((size_t)b * 1024 + ot * 64) * 256 + m;
  for (int o = 0; o < 64; ++o){
    float acc = 0.f;
#pragma unroll
    for (int c = 0; c < 64; ++c) acc += w2s[o][c] * feat[c];
    xb[(size_t)o * 256] = f2bf(acc);
  }
}

// FUSED 1: blocks [0,32) = FPS stage1; blocks [32,544) = x_skip pre
__global__ __launch_bounds__(256) void kfused1(const float* __restrict__ x,
                                               const u16* __restrict__ featT, const float* __restrict__ w2,
                                               u16* __restrict__ xpre,
                                               int* __restrict__ fidx1, float* __restrict__ nxyz1){
  if (blockIdx.x < 32){
    fps_body<1024, 512, 1>(x, x + 1024, x + 2048, 6144, fidx1, nxyz1, blockIdx.x);
  } else {
    xskip_body(featT, w2, xpre, blockIdx.x - 32);
  }
}

__global__ __launch_bounds__(256) void kxskip_stats(const u16* __restrict__ xpre, const float* __restrict__ g,
                                                    const float* __restrict__ b, float* __restrict__ sc,
                                                    float* __restrict__ sh){
  int o = blockIdx.x, t = threadIdx.x;
  float s = 0.f, ss = 0.f;
  for (int i = t; i < 8192; i += 256){
    int bb = i >> 8, m = i & 255;
    float v = bf2f(xpre[((size_t)bb * 1024 + o) * 256 + m]);
    s += v; ss += v * v;
  }
  __shared__ float rs[256], rq[256];
  rs[t] = s; rq[t] = ss; __syncthreads();
  for (int k = 128; k >= 1; k >>= 1){
    if (t < k){ rs[t] += rs[t + k]; rq[t] += rq[t + k]; }
    __syncthreads();
  }
  if (t == 0){
    float m = rs[0] * (1.f / 8192.f), e2 = rq[0] * (1.f / 8192.f);
    float var = e2 - m * m; if (var < 0.f) var = 0.f;
    float scv = g[o] * rsqrtf(var + BN_EPS);
    sc[o] = scv; sh[o] = b[o] - m * scv;
  }
}

// ---------------------------------------------------------------- kNN: two-phase DPP argmin, 4 waves/block
template<int NPTS, int SOUT>
__global__ __launch_bounds__(256) void kknn(const float* __restrict__ px_, const float* __restrict__ py_,
                                            const float* __restrict__ pz_, int bstride, int pstride,
                                            const float* __restrict__ cxyz, int* __restrict__ knn){
  constexpr int PPL = NPTS / 64;
  int wid = blockIdx.x * 4 + (threadIdx.x >> 6);
  int lane = threadIdx.x & 63;
  int b = wid / SOUT, s = wid - b * SOUT;
  const float* cb = cxyz + ((size_t)b * SOUT + s) * 3;
  float cx = cb[0], cy = cb[1], cz = cb[2];
  float csq = __fadd_rn(__fadd_rn(__fmul_rn(cx, cx), __fmul_rn(cy, cy)), __fmul_rn(cz, cz));
  float kd[PPL];
#pragma unroll
  for (int j = 0; j < PPL; ++j){
    int p = j * 64 + lane;
    float xx = px_[(size_t)b * bstride + p * pstride];
    float yy = py_[(size_t)b * bstride + p * pstride];
    float zz = pz_[(size_t)b * bstride + p * pstride];
    float psq = __fadd_rn(__fadd_rn(__fmul_rn(xx, xx), __fmul_rn(yy, yy)), __fmul_rn(zz, zz));
    float dot = __fadd_rn(__fadd_rn(__fmul_rn(cx, xx), __fmul_rn(cy, yy)), __fmul_rn(cz, zz));
    kd[j] = __fsub_rn(__fadd_rn(csq, psq), __fmul_rn(2.f, dot));
  }
  int* outp = knn + ((size_t)b * SOUT + s) * 32;
  for (int k = 0; k < 32; ++k){
    float bd = kd[0]; u32 bi = (u32)lane;
#pragma unroll
    for (int j = 1; j < PPL; ++j){
      u32 p = (u32)(j * 64 + lane);
      if (kd[j] < bd){ bd = kd[j]; bi = p; }   // strict < keeps lowest j
    }
    u32 win = arg_reduce2<false>(bd, bi);
    if (lane == 0) outp[k] = (int)win;
#pragma unroll
    for (int j = 0; j < PPL; ++j) if ((u32)(j * 64 + lane) == win) kd[j] = 3e38f;
  }
}

// ---------------------------------------------------------------- kgm_pre body: gather + GEMM1 -> pre1 + partials
template<int CIN, int C, int NPTSRC, int SLOG>
DEV void kgm_pre_body(const u16* __restrict__ featSrc, const int* __restrict__ knnIdx,
                      const int* __restrict__ fidx, const float* __restrict__ w1f,
                      const u16* __restrict__ w1bf,
                      u16* __restrict__ pre1, float* __restrict__ part, int g){
  constexpr int MT  = C / 64;
  constexpr int KS1 = CIN / 32;
  constexpr int P1  = CIN + 8;
  int t = threadIdx.x, b = g >> SLOG;
  int l = t & 63, wv = t >> 6;
  int lg = l >> 4, ln = l & 15;

  __shared__ int   idxs[32];
  __shared__ float cen[CIN];
  __shared__ float bias[C];
  __shared__ u16   gsT[32][P1];

  if (t < 32) idxs[t] = knnIdx[(size_t)g * 32 + t];
  for (int u = t; u < CIN; u += 256) cen[u] = bf2f(featSrc[((size_t)(b * NPTSRC + fidx[g])) * CIN + u]);
  __syncthreads();

  for (int u = t; u < 32 * CIN / 8; u += 256){
    int k = u & 31, c8 = u >> 5;
    uint4 pv = *(const uint4*)(featSrc + ((size_t)(b * NPTSRC + idxs[k])) * CIN + c8 * 8);
    u32 wvv[4] = {pv.x, pv.y, pv.z, pv.w};
    u32 outw[4];
#pragma unroll
    for (int h = 0; h < 4; ++h){
      float a0 = bf2f((u16)(wvv[h] & 0xffff)) - cen[c8 * 8 + 2 * h];
      float a1 = bf2f((u16)(wvv[h] >> 16))    - cen[c8 * 8 + 2 * h + 1];
      outw[h] = (u32)f2bf(a0) | ((u32)f2bf(a1) << 16);
    }
    *(uint4*)&gsT[k][c8 * 8] = make_uint4(outw[0], outw[1], outw[2], outw[3]);
  }
  if (t < C){
    const float* wr = w1f + (size_t)t * (2 * CIN) + CIN;
    float bs = 0.f;
#pragma unroll 4
    for (int c = 0; c < CIN; ++c) bs += wr[c] * cen[c];
    bias[t] = bs;
  }
  __syncthreads();

  f32x4 acc[MT][2];
#pragma unroll
  for (int mt = 0; mt < MT; ++mt){ acc[mt][0] = (f32x4)0.f; acc[mt][1] = (f32x4)0.f; }
#pragma unroll
  for (int ks = 0; ks < KS1; ++ks){
    int c0 = ks * 32 + lg * 8;
    bf16x8 bfr0 = *(const bf16x8*)&gsT[ln][c0];
    bf16x8 bfr1 = *(const bf16x8*)&gsT[16 + ln][c0];
#pragma unroll
    for (int mt = 0; mt < MT; ++mt){
      int o0 = wv * (C / 4) + mt * 16;
      bf16x8 afr = *(const bf16x8*)(w1bf + (size_t)(o0 + ln) * CIN + c0);
      acc[mt][0] = __builtin_amdgcn_mfma_f32_16x16x32_bf16(afr, bfr0, acc[mt][0], 0, 0, 0);
      acc[mt][1] = __builtin_amdgcn_mfma_f32_16x16x32_bf16(afr, bfr1, acc[mt][1], 0, 0, 0);
    }
  }

#pragma unroll
  for (int mt = 0; mt < MT; ++mt){
    int obase = wv * (C / 4) + mt * 16 + lg * 4;
#pragma unroll
    for (int j = 0; j < 4; ++j){
      int o = obase + j;
      float bv = bias[o];
      float vA = acc[mt][0][j] + bv, vB = acc[mt][1][j] + bv;
      u16* pp = pre1 + ((size_t)g * C + o) * 32 + ln;
      pp[0]  = f2bf(vA);
      pp[16] = f2bf(vB);
      float s = vA + vB, ss = vA * vA + vB * vB;
#pragma unroll
      for (int mk = 1; mk < 16; mk <<= 1){ s += __shfl_xor(s, mk, 64); ss += __shfl_xor(ss, mk, 64); }
      if (ln == 0){
        part[((size_t)g * C + o) * 2 + 0] = s;
        part[((size_t)g * C + o) * 2 + 1] = ss;
      }
    }
  }
}

// standalone kgm_pre (stage 2)
template<int CIN, int C, int NPTSRC, int SLOG>
__global__ __launch_bounds__(256) void kgm_pre(const u16* __restrict__ featSrc, const int* __restrict__ knnIdx,
                                               const int* __restrict__ fidx, const float* __restrict__ w1f,
                                               const u16* __restrict__ w1bf,
                                               u16* __restrict__ pre1, float* __restrict__ part){
  kgm_pre_body<CIN, C, NPTSRC, SLOG>(featSrc, knnIdx, fidx, w1f, w1bf, pre1, part, blockIdx.x);
}

// FUSED 2: blocks [0,32) = FPS stage2; blocks [32, 32+16384) = kgm_pre stage1
__global__ __launch_bounds__(256) void kfused2(const float* __restrict__ nxyz1_,
                                               int* __restrict__ fidx2, float* __restrict__ nxyz2,
                                               const u16* __restrict__ featT, const int* __restrict__ knn1,
                                               const int* __restrict__ fidx1, const float* __restrict__ l0w1,
                                               const u16* __restrict__ w1bf1,
                                               u16* __restrict__ pre1, float* __restrict__ part){
  if (blockIdx.x < 32){
    fps_body<512, 256, 3>(nxyz1_, nxyz1_ + 1, nxyz1_ + 2, 1536, fidx2, nxyz2, blockIdx.x);
  } else {
    kgm_pre_body<64, 128, 1024, 9>(featT, knn1, fidx1, l0w1, w1bf1, pre1, part, blockIdx.x - 32);
  }
}

// ---------------------------------------------------------------- pass 2: pre1 -> BN1+ReLU -> GEMM2 -> partials + pool
template<int C>
__global__ __launch_bounds__(256) void kgm_post(const u16* __restrict__ pre1,
                                                const float* __restrict__ sc1g, const float* __restrict__ sh1g,
                                                const u16* __restrict__ w2bf, const float* __restrict__ gp,
                                                float* __restrict__ part, float* __restrict__ pooledPre){
  constexpr int MT  = C / 64;
  constexpr int KS2 = C / 32;
  constexpr int P2  = C + 8;
  int g = blockIdx.x, t = threadIdx.x;
  int l = t & 63, wv = t >> 6;
  int lg = l >> 4, ln = l & 15;

  __shared__ u16   act2[32][P2];
  __shared__ float sc1s[C], sh1s[C];
  for (int u = t; u < C; u += 256){ sc1s[u] = sc1g[u]; sh1s[u] = sh1g[u]; }
  __syncthreads();

  for (int u = t; u < C * 4; u += 256){
    uint4 pv = *(const uint4*)(pre1 + (size_t)g * C * 32 + (size_t)u * 8);
    int o = u >> 2, k0 = (u & 3) << 3;
    float s1 = sc1s[o], h1 = sh1s[o];
    u32 wvv[4] = {pv.x, pv.y, pv.z, pv.w};
#pragma unroll
    for (int h = 0; h < 4; ++h){
      float a0 = fmaxf(s1 * bf2f((u16)(wvv[h] & 0xffff)) + h1, 0.f);
      float a1 = fmaxf(s1 * bf2f((u16)(wvv[h] >> 16))    + h1, 0.f);
      act2[k0 + 2 * h][o]     = f2bf(a0);
      act2[k0 + 2 * h + 1][o] = f2bf(a1);
    }
  }
  __syncthreads();

  f32x4 acc[MT][2];
#pragma unroll
  for (int mt = 0; mt < MT; ++mt){ acc[mt][0] = (f32x4)0.f; acc[mt][1] = (f32x4)0.f; }
#pragma unroll
  for (int ks = 0; ks < KS2; ++ks){
    int c0 = ks * 32 + lg * 8;
    bf16x8 bfr0 = *(const bf16x8*)&act2[ln][c0];
    bf16x8 bfr1 = *(const bf16x8*)&act2[16 + ln][c0];
#pragma unroll
    for (int mt = 0; mt < MT; ++mt){
      int o0 = wv * (C / 4) + mt * 16;
      bf16x8 afr = *(const bf16x8*)(w2bf + (size_t)(o0 + ln) * C + c0);
      acc[mt][0] = __builtin_amdgcn_mfma_f32_16x16x32_bf16(afr, bfr0, acc[mt][0], 0, 0, 0);
      acc[mt][1] = __builtin_amdgcn_mfma_f32_16x16x32_bf16(afr, bfr1, acc[mt][1], 0, 0, 0);
    }
  }

#pragma unroll
  for (int mt = 0; mt < MT; ++mt){
    int obase = wv * (C / 4) + mt * 16 + lg * 4;
#pragma unroll
    for (int j = 0; j < 4; ++j){
      float vA = acc[mt][0][j], vB = acc[mt][1][j];
      float s = vA + vB, ss = vA * vA + vB * vB;
      float mx = fmaxf(vA, vB), mn = fminf(vA, vB);
#pragma unroll
      for (int mk = 1; mk < 16; mk <<= 1){
        s += __shfl_xor(s, mk, 64); ss += __shfl_xor(ss, mk, 64);
        mx = fmaxf(mx, __shfl_xor(mx, mk, 64)); mn = fminf(mn, __shfl_xor(mn, mk, 64));
      }
      if (ln == 0){
        int o = obase + j;
        part[((size_t)g * C + o) * 2 + 0] = s;
        part[((size_t)g * C + o) * 2 + 1] = ss;
        pooledPre[(size_t)g * C + o] = (gp[o] >= 0.f) ? mx : mn;
      }
    }
  }
}

// reduce per-group partials -> BN scale/shift (deterministic)
template<int C, int NG>
__global__ __launch_bounds__(256) void kstats_part(const float* __restrict__ part, const float* __restrict__ g_,
                                                   const float* __restrict__ b_, float* __restrict__ sc,
                                                   float* __restrict__ sh){
  int o = blockIdx.x, t = threadIdx.x;
  float s = 0.f, ss = 0.f;
  for (int i = t; i < NG; i += 256){
    s  += part[((size_t)i * C + o) * 2 + 0];
    ss += part[((size_t)i * C + o) * 2 + 1];
  }
  __shared__ float rs[256], rq[256];
  rs[t] = s; rq[t] = ss; __syncthreads();
  for (int k = 128; k >= 1; k >>= 1){
    if (t < k){ rs[t] += rs[t + k]; rq[t] += rq[t + k]; }
    __syncthreads();
  }
  if (t == 0){
    const float inv_n = 1.f / (float)(NG * 32);
    float m = rs[0] * inv_n, e2 = rq[0] * inv_n;
    float var = e2 - m * m; if (var < 0.f) var = 0.f;
    float scv = g_[o] * rsqrtf(var + BN_EPS);
    sc[o] = scv; sh[o] = b_[o] - m * scv;
  }
}

// finalize pooled (stage1): f0feat bf16 [b*512+s][128]
__global__ void kpool_fin1(const float* __restrict__ pooledPre, const float* __restrict__ sc,
                           const float* __restrict__ sh, u16* __restrict__ f0feat){
  int i = blockIdx.x * 256 + threadIdx.x;
  if (i >= 16384 * 128) return;
  int o = i & 127;
  float v = sc[o] * pooledPre[i] + sh[o];
  f0feat[i] = f2bf(fmaxf(v, 0.f));
}

// finalize pooled (stage2): f1T bf16 [b][c][s]
__global__ void kpool_finT(const float* __restrict__ pooledPre, const float* __restrict__ sc,
                           const float* __restrict__ sh, u16* __restrict__ f1T){
  int i = blockIdx.x * 256 + threadIdx.x;
  if (i >= 8192 * 256) return;
  int gg = i >> 8, o = i & 255;
  int b = gg >> 8, s = gg & 255;
  float v = sc[o] * pooledPre[i] + sh[o];
  f1T[((size_t)(b * 256 + o)) * 256 + s] = f2bf(fmaxf(v, 0.f));
}

// ---------------------------------------------------------------- final GEMM: block = (b, 8-o tile), thread = m
__global__ __launch_bounds__(256) void kfinal8(const u16* __restrict__ f1T, const u16* __restrict__ xpre,
                                               const float* __restrict__ scS, const float* __restrict__ shS,
                                               const float* __restrict__ wf, u16* __restrict__ finpre){
  int b = blockIdx.x >> 6, ot = blockIdx.x & 63, m = threadIdx.x;
  int o0 = ot * 8;
  const float* wb = wf + (size_t)o0 * 1280;
  float acc[8];
#pragma unroll
  for (int j = 0; j < 8; ++j) acc[j] = 0.f;
  const u16* fb = f1T + (size_t)b * 256 * 256 + m;
  for (int k = 0; k < 256; ++k){
    float v = bf2f(fb[(size_t)k * 256]);
#pragma unroll
    for (int j = 0; j < 8; ++j) acc[j] = fmaf(wb[(size_t)j * 1280 + k], v, acc[j]);
  }
  const u16* xb = xpre + (size_t)b * 1024 * 256 + m;
  for (int k = 0; k < 1024; ++k){
    float xv = bf2f(xb[(size_t)k * 256]);
    float v = fmaxf(scS[k] * xv + shS[k], 0.f);
#pragma unroll
    for (int j = 0; j < 8; ++j) acc[j] = fmaf(wb[(size_t)j * 1280 + 256 + k], v, acc[j]);
  }
#pragma unroll
  for (int j = 0; j < 8; ++j)
    finpre[((size_t)b * 512 + o0 + j) * 256 + m] = f2bf(acc[j]);
}

__global__ __launch_bounds__(256) void kstats_fin(const u16* __restrict__ finpre, const float* __restrict__ g,
                                                  const float* __restrict__ b, float* __restrict__ sc,
                                                  float* __restrict__ sh){
  int o = blockIdx.x, t = threadIdx.x;
  float s = 0.f, ss = 0.f;
  for (int i = t; i < 8192; i += 256){
    int bb = i >> 8, m = i & 255;
    float v = bf2f(finpre[((size_t)bb * 512 + o) * 256 + m]);
    s += v; ss += v * v;
  }
  __shared__ float rs[256], rq[256];
  rs[t] = s; rq[t] = ss; __syncthreads();
  for (int k = 128; k >= 1; k >>= 1){
    if (t < k){ rs[t] += rs[t + k]; rq[t] += rq[t + k]; }
    __syncthreads();
  }
  if (t == 0){
    float m = rs[0] * (1.f / 8192.f), e2 = rq[0] * (1.f / 8192.f);
    float var = e2 - m * m; if (var < 0.f) var = 0.f;
    float scv = g[o] * rsqrtf(var + BN_EPS);
    sc[o] = scv; sh[o] = b[o] - m * scv;
  }
}

__global__ void kapply(const u16* __restrict__ finpre, const float* __restrict__ sc,
                       const float* __restrict__ sh, float* __restrict__ out){
  int i = blockIdx.x * 256 + threadIdx.x;
  if (i >= 32 * 512 * 256) return;
  int o = (i >> 8) & 511;
  float v = sc[o] * bf2f(finpre[i]) + sh[o];
  out[i] = v > 0.f ? v : 0.2f * v;
}

// ================================================================ host
extern "C" void kernel_launch(void* const* d_in, const int* in_sizes, int n_in,
                              void* d_out, int out_size, void* d_ws, size_t ws_size,
                              hipStream_t stream){
  const float* x    = (const float*)d_in[0];
  const float* w_c1 = (const float*)d_in[1];
  const float* g1   = (const float*)d_in[2];
  const float* b1   = (const float*)d_in[3];
  const float* w_c2 = (const float*)d_in[4];
  const float* g2   = (const float*)d_in[5];
  const float* b2   = (const float*)d_in[6];
  const float* l0w1 = (const float*)d_in[7];
  const float* l0g1 = (const float*)d_in[8];
  const float* l0b1 = (const float*)d_in[9];
  const float* l0w2 = (const float*)d_in[10];
  const float* l0g2 = (const float*)d_in[11];
  const float* l0b2 = (const float*)d_in[12];
  const float* l1w1 = (const float*)d_in[13];
  const float* l1g1 = (const float*)d_in[14];
  const float* l1b1 = (const float*)d_in[15];
  const float* l1w2 = (const float*)d_in[16];
  const float* l1g2 = (const float*)d_in[17];
  const float* l1b2 = (const float*)d_in[18];
  const float* wf   = (const float*)d_in[19];
  const float* gf   = (const float*)d_in[20];
  const float* bfp  = (const float*)d_in[21];
  float* out = (float*)d_out;

  char* ws = (char*)d_ws;
  size_t cur = 0;
  auto alloc = [&](size_t bytes) -> char* {
    char* p = ws + cur;
    cur += (bytes + 255) & ~(size_t)255;
    return p;
  };
  float* sc1  = (float*)alloc(64 * 4);    float* sh1  = (float*)alloc(64 * 4);
  float* scSK = (float*)alloc(1024 * 4);  float* shSK = (float*)alloc(1024 * 4);
  float* scA1 = (float*)alloc(128 * 4);   float* shA1 = (float*)alloc(128 * 4);
  float* scA2 = (float*)alloc(128 * 4);   float* shA2 = (float*)alloc(128 * 4);
  float* scC1 = (float*)alloc(256 * 4);   float* shC1 = (float*)alloc(256 * 4);
  float* scC2 = (float*)alloc(256 * 4);   float* shC2 = (float*)alloc(256 * 4);
  float* scF  = (float*)alloc(512 * 4);   float* shF  = (float*)alloc(512 * 4);
  u16* w1bf1 = (u16*)alloc((size_t)128 * 64 * 2);
  u16* w2bf1 = (u16*)alloc((size_t)128 * 128 * 2);
  u16* w1bf2 = (u16*)alloc((size_t)256 * 128 * 2);
  u16* w2bf2 = (u16*)alloc((size_t)256 * 256 * 2);
  u16*   featT  = (u16*)  alloc((size_t)32 * 1024 * 64 * 2);
  u16*   xpre   = (u16*)  alloc((size_t)32 * 1024 * 256 * 2);
  int*   fidx1  = (int*)  alloc((size_t)32 * 512 * 4);
  float* nxyz1  = (float*)alloc((size_t)32 * 512 * 3 * 4);
  int*   knn1   = (int*)  alloc((size_t)32 * 512 * 32 * 4);
  int*   fidx2  = (int*)  alloc((size_t)32 * 256 * 4);
  float* nxyz2  = (float*)alloc((size_t)32 * 256 * 3 * 4);
  int*   knn2   = (int*)  alloc((size_t)32 * 256 * 32 * 4);
  u16*   pre1   = (u16*)  alloc((size_t)16384 * 128 * 32 * 2);  // == 8192*256*32, reused by stage 2
  float* part   = (float*)alloc((size_t)16384 * 128 * 2 * 4);   // == 8192*256*2, reused by stage 2
  float* pooledPre = (float*)alloc((size_t)16384 * 128 * 4);    // == 8192*256, reused by stage 2
  u16*   f0feat = (u16*)  alloc((size_t)16384 * 128 * 2);
  u16*   f1T    = (u16*)  alloc((size_t)32 * 256 * 256 * 2);
  u16*   finpre = (u16*)  alloc((size_t)32 * 512 * 256 * 2);

  if (cur > ws_size){
    float code = -1000.f - (float)(ws_size >> 20);
    kfb<<<(out_size + 255) / 256, 256, 0, stream>>>(out, out_size, code);
    return;
  }

  // bf16 weight casts (left half of w1; full w2)
  kcast_bf<<<(128 * 64 + 255) / 256, 256, 0, stream>>>(l0w1, 128, 64, 128, 0, w1bf1);
  kcast_bf<<<(128 * 128 + 255) / 256, 256, 0, stream>>>(l0w2, 128, 128, 128, 0, w2bf1);
  kcast_bf<<<(256 * 128 + 255) / 256, 256, 0, stream>>>(l1w1, 256, 128, 256, 0, w1bf2);
  kcast_bf<<<(256 * 256 + 255) / 256, 256, 0, stream>>>(l1w2, 256, 256, 256, 0, w2bf2);

  // stage A
  kA_stats<<<64, 256, 0, stream>>>(x, w_c1, g1, b1, sc1, sh1);
  kA_feat<<<128, 256, 0, stream>>>(x, w_c1, sc1, sh1, featT);

  // FUSED 1: FPS stage1 (32 blocks) || x_skip pre (512 blocks)
  kfused1<<<544, 256, 0, stream>>>(x, featT, w_c2, xpre, fidx1, nxyz1);
  kxskip_stats<<<1024, 256, 0, stream>>>(xpre, g2, b2, scSK, shSK);

  // stage 1 kNN
  kknn<1024, 512><<<32 * 512 / 4, 256, 0, stream>>>(x, x + 1024, x + 2048, 6144, 1, nxyz1, knn1);

  // FUSED 2: FPS stage2 (32 blocks) || kgm_pre stage1 (16384 blocks)
  kfused2<<<32 + 16384, 256, 0, stream>>>(nxyz1, fidx2, nxyz2,
                                          featT, knn1, fidx1, l0w1, w1bf1, pre1, part);
  kstats_part<128, 16384><<<128, 256, 0, stream>>>(part, l0g1, l0b1, scA1, shA1);
  kgm_post<128><<<16384, 256, 0, stream>>>(pre1, scA1, shA1, w2bf1, l0g2, part, pooledPre);
  kstats_part<128, 16384><<<128, 256, 0, stream>>>(part, l0g2, l0b2, scA2, shA2);
  kpool_fin1<<<8192, 256, 0, stream>>>(pooledPre, scA2, shA2, f0feat);

  // stage 2 kNN (nxyz2 ready after kfused2)
  kknn<512, 256><<<32 * 256 / 4, 256, 0, stream>>>(nxyz1, nxyz1 + 1, nxyz1 + 2, 1536, 3, nxyz2, knn2);

  // stage 2 local_op
  kgm_pre<128, 256, 512, 8><<<8192, 256, 0, stream>>>(f0feat, knn2, fidx2, l1w1, w1bf2, pre1, part);
  kstats_part<256, 8192><<<256, 256, 0, stream>>>(part, l1g1, l1b1, scC1, shC1);
  kgm_post<256><<<8192, 256, 0, stream>>>(pre1, scC1, shC1, w2bf2, l1g2, part, pooledPre);
  kstats_part<256, 8192><<<256, 256, 0, stream>>>(part, l1g2, l1b2, scC2, shC2);
  kpool_finT<<<8192, 256, 0, stream>>>(pooledPre, scC2, shC2, f1T);

  // final
  kfinal8<<<2048, 256, 0, stream>>>(f1T, xpre, scSK, shSK, wf, finpre);
  kstats_fin<<<512, 256, 0, stream>>>(finpre, gf, bfp, scF, shF);
  kapply<<<16384, 256, 0, stream>>>(finpre, scF, shF, out);
}